// Round 6
// baseline (17186.369 us; speedup 1.0000x reference)
//
#include <hip/hip_runtime.h>
#include <cstdint>
#include <cmath>

// Problem constants
#define B_    8
#define H_    72
#define W_    72
#define C_    16
#define C3_   48
#define HP_   16
#define HE_   128
#define T_    64
#define NCELL 41472      // B*H*W

typedef __attribute__((ext_vector_type(2))) double d2;

// ---------------------------------------------------------------------------
// JAX threefry2x32 (20 rounds)
// ---------------------------------------------------------------------------
__host__ __device__ __forceinline__ void threefry2x32(uint32_t k0, uint32_t k1,
                                                      uint32_t& x0, uint32_t& x1) {
  uint32_t ks2 = k0 ^ k1 ^ 0x1BD11BDAu;
  x0 += k0; x1 += k1;
#define TF_R(r) { x0 += x1; x1 = (x1 << (r)) | (x1 >> (32 - (r))); x1 ^= x0; }
  TF_R(13) TF_R(15) TF_R(26) TF_R(6)
  x0 += k1; x1 += ks2 + 1u;
  TF_R(17) TF_R(29) TF_R(16) TF_R(24)
  x0 += ks2; x1 += k0 + 2u;
  TF_R(13) TF_R(15) TF_R(26) TF_R(6)
  x0 += k0; x1 += k1 + 3u;
  TF_R(17) TF_R(29) TF_R(16) TF_R(24)
  x0 += k1; x1 += ks2 + 4u;
  TF_R(13) TF_R(15) TF_R(26) TF_R(6)
  x0 += ks2; x1 += k0 + 5u;
#undef TF_R
}

// ---------------------------------------------------------------------------
// init: f32 input -> f64 state; un = 1
// ---------------------------------------------------------------------------
__global__ void k_init(const float* __restrict__ xin, double* __restrict__ xA,
                       double* __restrict__ un) {
  int idx = blockIdx.x * 256 + threadIdx.x;
  if (idx < NCELL * C_) xA[idx] = (double)xin[idx];
  if (idx < NCELL) un[idx] = 1.0;
}

// ---------------------------------------------------------------------------
// prep (once): effective 5x5 conv1 weights (conv1 o perceive, exact f64
// combination) + transposed f32 fc0 ([e][k], exact copy).
// ---------------------------------------------------------------------------
__global__ void k_prep(const float* __restrict__ w1, const float* __restrict__ f0w,
                       double* __restrict__ weffd, float* __restrict__ fc0tf) {
  int gid = blockIdx.x * 256 + threadIdx.x;
  const int stride = 26 * 256;
  // w_eff[u][v][ic][oc]
  for (int t = gid; t < 6400; t += stride) {
    int oc = t & 15;
    int c  = (t >> 4) & 15;
    int pos = t >> 8;             // 0..24
    int u = pos / 5, v = pos % 5;
    double acc = 0.0;
    for (int ei = 0; ei < 3; ei++) {
      int di = u - ei; if (di < 0 || di > 2) continue;
      for (int ej = 0; ej < 3; ej++) {
        int dj = v - ej; if (dj < 0 || dj > 2) continue;
        const float* wb = w1 + (size_t)((ei * 3 + ej) * C3_) * HP_ + oc;
        if (di == 1 && dj == 1) acc += (double)wb[c * HP_];
        double rf1 = (di == 0) ? -0.125 : (di == 2) ? 0.125 : 0.0;
        if (rf1 != 0.0) {
          double cf1 = (dj == 1) ? 2.0 : 1.0;
          acc += (double)wb[(C_ + c) * HP_] * (rf1 * cf1);
        }
        double cf2 = (dj == 0) ? -0.125 : (dj == 2) ? 0.125 : 0.0;
        if (cf2 != 0.0) {
          double rf2 = (di == 1) ? 2.0 : 1.0;
          acc += (double)wb[(2 * C_ + c) * HP_] * (cf2 * rf2);
        }
      }
    }
    weffd[t] = acc;
  }
  // fc0 transposed: fc0tf[e*48 + k] = f0w[k*128 + e]  (f32, exact)
  for (int t = gid; t < C3_ * HE_; t += stride) {
    int k = t >> 7, e = t & 127;
    fc0tf[e * C3_ + k] = f0w[t];
  }
}

// ---------------------------------------------------------------------------
// conv1 fused with perceive. Block = (b, i, half-row h): 36 cells x 8 oc-pairs
// = 288 threads. x halo tile (5 rows x 40 cols x 16 ch, zero-padded) staged in
// LDS; w_eff (f64) in LDS. Inner loop: pure LDS reads + FMA, no global.
// Ring cells: exact two-stage path (global x, f32 w1) per thread, 2 oc.
// Grid: 8*72*2 = 1152 blocks.
// ---------------------------------------------------------------------------
__global__ void __launch_bounds__(288) k_conv1(const double* __restrict__ x,
    const double* __restrict__ weffd, const float* __restrict__ w1f,
    const float* __restrict__ b1f, double* __restrict__ hbuf) {
  __shared__ double sw[6400];   // [pos][ic][oc]   51.2 KB
  __shared__ double sx[3200];   // [u][col][ic]    25.6 KB
  int tid = threadIdx.x;
  int bid = blockIdx.x;
  int h = bid & 1;
  int t2 = bid >> 1;
  int i = t2 % H_;
  int b = t2 / H_;
  int j0 = h * 36;
  // ---- stage weights ----
  for (int t = tid; t < 6400; t += 288) sw[t] = weffd[t];
  // ---- stage x tile with zero pad (matches zero-padded-x interior math) ----
  for (int e = tid; e < 1600; e += 288) {
    int icp = e & 7;
    int col = (e >> 3) % 40;
    int u = e / 320;
    int ii = i + u - 2;
    int jj = j0 - 2 + col;
    bool ok = ((unsigned)ii < (unsigned)H_) && ((unsigned)jj < (unsigned)W_);
    int iic = ok ? ii : 0, jjc = ok ? jj : 0;
    const double* src = x + (((size_t)((b * H_ + iic) * W_ + jjc)) << 4) + 2 * icp;
    d2 v = *(const d2*)src;
    sx[e * 2]     = ok ? v.x : 0.0;
    sx[e * 2 + 1] = ok ? v.y : 0.0;
  }
  __syncthreads();

  int ocp = tid & 7;
  int cs = tid >> 3;            // 0..35
  int j = j0 + cs;
  int cell = (b * H_ + i) * W_ + j;
  int oc0 = 2 * ocp;
  double bv0 = (double)b1f[oc0], bv1 = (double)b1f[oc0 + 1];
  bool ring = (i == 0 || i == H_ - 1 || j == 0 || j == W_ - 1);
  double r0, r1;
  if (!ring) {
    double aE0 = bv0, aE1 = bv1, aO0 = 0.0, aO1 = 0.0;
#pragma unroll
    for (int p = 0; p < 25; p++) {
      const int u = p / 5, v = p % 5;
      const double* xr = sx + (u * 40 + cs + v) * 16;
      const double* wp = sw + p * 256 + oc0;
#pragma unroll
      for (int g = 0; g < 8; g++) {
        d2 xv = *(const d2*)(xr + 2 * g);
        d2 w0 = *(const d2*)(wp + (2 * g) * 16);
        d2 w1 = *(const d2*)(wp + (2 * g + 1) * 16);
        if (p & 1) {
          aO0 = fma(xv.x, w0.x, aO0); aO1 = fma(xv.x, w0.y, aO1);
          aO0 = fma(xv.y, w1.x, aO0); aO1 = fma(xv.y, w1.y, aO1);
        } else {
          aE0 = fma(xv.x, w0.x, aE0); aE1 = fma(xv.x, w0.y, aE1);
          aE0 = fma(xv.y, w1.x, aE0); aE1 = fma(xv.y, w1.y, aE1);
        }
      }
    }
    r0 = aE0 + aO0; r1 = aE1 + aO1;
  } else {
    // ---- boundary ring: exact two-stage (perc zero-pad semantics) ----
    double acc0 = bv0, acc1 = bv1;
    for (int ei = 0; ei < 3; ei++) {
      int pi = i + ei - 1; if (pi < 0 || pi >= H_) continue;
      for (int ej = 0; ej < 3; ej++) {
        int pj = j + ej - 1; if (pj < 0 || pj >= W_) continue;
        const float* wb = w1f + (size_t)((ei * 3 + ej) * C3_) * HP_ + oc0;
        for (int c = 0; c < C_; c++) {
          double v[3][3];
#pragma unroll
          for (int a2 = 0; a2 < 3; a2++) {
#pragma unroll
            for (int b2i = 0; b2i < 3; b2i++) {
              int ii2 = pi + a2 - 1, jj2 = pj + b2i - 1;
              bool ok = (ii2 >= 0 && ii2 < H_ && jj2 >= 0 && jj2 < W_);
              v[a2][b2i] = ok ? x[(((size_t)((b * H_ + ii2) * W_ + jj2)) << 4) + c] : 0.0;
            }
          }
          double ctr = v[1][1];
          double dw1 = (-v[0][0] - 2.0 * v[0][1] - v[0][2] + v[2][0] + 2.0 * v[2][1] + v[2][2]) * 0.125;
          double dw2 = (-v[0][0] + v[0][2] - 2.0 * v[1][0] + 2.0 * v[1][2] - v[2][0] + v[2][2]) * 0.125;
          acc0 += ctr * (double)wb[c * HP_]     + dw1 * (double)wb[(C_ + c) * HP_]     + dw2 * (double)wb[(2 * C_ + c) * HP_];
          acc1 += ctr * (double)wb[c * HP_ + 1] + dw1 * (double)wb[(C_ + c) * HP_ + 1] + dw2 * (double)wb[(2 * C_ + c) * HP_ + 1];
        }
      }
    }
    r0 = acc0; r1 = acc1;
  }
  double* hp = hbuf + ((size_t)cell << 4) + oc0;
  hp[0] = r0 > 0.0 ? r0 : 0.0;
  hp[1] = r1 > 0.0 ? r1 : 0.0;
}

// ---------------------------------------------------------------------------
// fused conv2 + update. 512 thr = 64 cells (lane) x 8 waves.
//  - f32 weights staged to LDS (exact f32->f64 cvt on use)
//  - cooperative perceive: wave wv computes channels 2wv,2wv+1 -> pv LDS
//  - each wave: pv->regs, MLP e-slice 16; waves 0-3 also conv2 ic-slice
//  - two-stage LDS reduction of dx/z partials; wave 0 does lambda/RNG/
//    bookkeeping/xn (verbatim).
// ---------------------------------------------------------------------------
__global__ void __launch_bounds__(512) k_upd(
    const double* __restrict__ x, const double* __restrict__ hbuf,
    const double* __restrict__ lamPrev, const float* __restrict__ fc0tf,
    const float* __restrict__ f1w, const float* __restrict__ w2f,
    const float* __restrict__ f0b, const float* __restrict__ b2,
    double* __restrict__ lamNext, double* __restrict__ xn,
    float* __restrict__ out_upd, double* __restrict__ un,
    float* __restrict__ out_lam, double* __restrict__ p_buf,
    uint32_t k0, uint32_t k1, int n) {
  __shared__ float s0f[HE_ * C3_];   // 24576 B  [e][k]
  __shared__ float s1f[HE_ * C_];    // 8192 B   [e][c]
  __shared__ float sw2[144];
  __shared__ float sb0[HE_];
  __shared__ double upool[4352];     // 34816 B: pv [64][51] / reduce [4][64][17]
  int tid = threadIdx.x;
  for (int t = tid; t < HE_ * C3_; t += 512) s0f[t] = fc0tf[t];
  for (int t = tid; t < HE_ * C_; t += 512) s1f[t] = f1w[t];
  if (tid < 144) sw2[tid] = w2f[tid];
  if (tid < HE_) sb0[tid] = f0b[tid];

  int lane = tid & 63;
  int wv = __builtin_amdgcn_readfirstlane(tid >> 6);  // 0..7
  int cell = (blockIdx.x << 6) + lane;
  int j = cell % W_; int t2 = cell / W_; int i = t2 % H_; int b = t2 / H_;

  // ---- cooperative perceive: this wave's 2 channels ----
  int c0 = wv * 2;
  double pA = 0.0, pB = 0.0;
  double q1A = 0.0, q1B = 0.0, q2A = 0.0, q2B = 0.0;
#pragma unroll
  for (int p = 0; p < 9; p++) {
    const int di = p / 3, dj = p % 3;
    const double k1c = (di == 0 ? -0.125 : di == 2 ? 0.125 : 0.0) * (dj == 1 ? 2.0 : 1.0);
    const double k2c = (dj == 0 ? -0.125 : dj == 2 ? 0.125 : 0.0) * (di == 1 ? 2.0 : 1.0);
    int ii = i + di - 1, jj = j + dj - 1;
    bool ok = ((unsigned)ii < (unsigned)H_) && ((unsigned)jj < (unsigned)W_);
    int iic = ok ? ii : 0;
    int jjc = ok ? jj : 0;
    const double* xp = x + (((size_t)((b * H_ + iic) * W_ + jjc)) << 4) + c0;
    d2 xa = *(const d2*)xp;
    double xv0 = ok ? xa.x : 0.0;
    double xv1 = ok ? xa.y : 0.0;
    if (p == 4) { pA += xv0; pB += xv1; }
    if (k1c != 0.0) { q1A = fma(k1c, xv0, q1A); q1B = fma(k1c, xv1, q1B); }
    if (k2c != 0.0) { q2A = fma(k2c, xv0, q2A); q2B = fma(k2c, xv1, q2B); }
  }
  {
    double* pr = upool + lane * 51;
    pr[c0] = pA; pr[c0 + 1] = pB;
    pr[16 + c0] = q1A; pr[16 + c0 + 1] = q1B;
    pr[32 + c0] = q2A; pr[32 + c0 + 1] = q2B;
  }
  __syncthreads();   // #1: weights staged + pv complete

  // ---- conv2 partial over ic slice (waves 0-3 only) ----
  double z = (wv == 0) ? (double)b2[0] : 0.0;
  if (wv < 4) {
    int cq = wv * 4;
    for (int di = 0; di < 3; di++) {
      int ii = i + di - 1; if (ii < 0 || ii >= H_) continue;
      for (int dj = 0; dj < 3; dj++) {
        int jj = j + dj - 1; if (jj < 0 || jj >= W_) continue;
        const double* hh = hbuf + (((size_t)((b * H_ + ii) * W_ + jj)) << 4) + cq;
        const float* ww = sw2 + (di * 3 + dj) * HP_ + cq;
        d2 h0 = *(const d2*)hh;
        d2 h1 = *(const d2*)(hh + 2);
        z = fma(h0.x, (double)ww[0], z);
        z = fma(h0.y, (double)ww[1], z);
        z = fma(h1.x, (double)ww[2], z);
        z = fma(h1.y, (double)ww[3], z);
      }
    }
  }

  // ---- pv -> registers (once) ----
  double pv[C3_];
#pragma unroll
  for (int k = 0; k < C3_; k++) pv[k] = upool[lane * 51 + k];

  // ---- MLP for e-slice [wv*16, wv*16+16); f32 weights cvt'd (exact) ----
  double dx[C_];
#pragma unroll
  for (int c = 0; c < C_; c++) dx[c] = 0.0;
  int ebase = wv << 4;   // uniform
#pragma unroll 1
  for (int eg = 0; eg < 16; eg += 4) {
    int e = ebase + eg;
    const float* w0 = s0f + e * C3_;    // uniform address -> LDS broadcast
    double a0 = (double)sb0[e + 0];
    double a1 = (double)sb0[e + 1];
    double a2 = (double)sb0[e + 2];
    double a3 = (double)sb0[e + 3];
#pragma unroll
    for (int k = 0; k < C3_; k++) {
      a0 = fma(pv[k], (double)w0[k], a0);
      a1 = fma(pv[k], (double)w0[C3_ + k], a1);
      a2 = fma(pv[k], (double)w0[2 * C3_ + k], a2);
      a3 = fma(pv[k], (double)w0[3 * C3_ + k], a3);
    }
    a0 = a0 > 0.0 ? a0 : 0.0;
    a1 = a1 > 0.0 ? a1 : 0.0;
    a2 = a2 > 0.0 ? a2 : 0.0;
    a3 = a3 > 0.0 ? a3 : 0.0;
    const float* v0 = s1f + (e << 4);   // uniform
#pragma unroll
    for (int c = 0; c < C_; c++) {
      double s = fma(a0, (double)v0[c], dx[c]);
      s = fma(a1, (double)v0[16 + c], s);
      s = fma(a2, (double)v0[32 + c], s);
      s = fma(a3, (double)v0[48 + c], s);
      dx[c] = s;
    }
  }

  __syncthreads();   // #2: all pv reads done; upool reusable
  // ---- stage A: waves 4-7 -> waves 0-3 ----
  if (wv >= 4) {
    double* pr = upool + (wv - 4) * 1088 + lane * 17;
#pragma unroll
    for (int c = 0; c < C_; c++) pr[c] = dx[c];
  }
  __syncthreads();   // #3
  if (wv < 4) {
    const double* pr = upool + wv * 1088 + lane * 17;
#pragma unroll
    for (int c = 0; c < C_; c++) dx[c] += pr[c];
  }
  __syncthreads();   // #4: stage-A reads done
  // ---- stage B: waves 1-3 -> wave 0 ----
  if (wv >= 1 && wv < 4) {
    double* pr = upool + (wv - 1) * 1088 + lane * 17;
#pragma unroll
    for (int c = 0; c < C_; c++) pr[c] = dx[c];
    pr[16] = z;
  }
  __syncthreads();   // #5
  if (wv != 0) return;

#pragma unroll
  for (int w = 0; w < 3; w++) {
    const double* pr = upool + w * 1088 + lane * 17;
#pragma unroll
    for (int c = 0; c < C_; c++) dx[c] += pr[c];
    z += pr[16];
  }

  double lamF = 1.0 / (1.0 + exp(-z));
  lamNext[cell] = lamF;
  double l = (n == 0) ? lamF : lamPrev[cell];

  // ---- scan bookkeeping with lagged lam ----
  if (n >= 1) {
    size_t o = (size_t)(n - 1) * NCELL + cell;
    out_lam[o] = (float)l;
    double u = un[cell];
    p_buf[o] = u * l + 1e-6;
    un[cell] = u * (1.0 - l);
  }

  // ---- RNG + state write ----
  uint32_t r0 = 0u, r1 = (uint32_t)cell;
  threefry2x32(k0, k1, r0, r1);
  double uf = (double)(r0 ^ r1) * 0x1p-32;
  double upd = (uf < l) ? 0.0 : 1.0;
  out_upd[(size_t)n * NCELL + cell] = (float)upd;
  const double* xc = x + ((size_t)cell << 4);
  double* xo = xn + ((size_t)cell << 4);
#pragma unroll
  for (int c = 0; c < C_; c++) xo[c] = xc[c] + dx[c] * upd;
}

// ---------------------------------------------------------------------------
// life mask: x_new = xn * (alive(x_old) & alive(xn)); emit x_steps[n]
// thread = (cell, c)
// ---------------------------------------------------------------------------
__global__ void k_life(const double* __restrict__ xold, const double* __restrict__ xn,
                       double* __restrict__ xout, float* __restrict__ out_x, int n) {
  int idx = blockIdx.x * 256 + threadIdx.x;
  int c = idx & 15;
  int cell = idx >> 4;
  int j = cell % W_; int t = cell / W_; int i = t % H_; int b = t / H_;
  double mo = -1e300, mn2 = -1e300;
  for (int di = -1; di <= 1; di++) {
    int ii = i + di; if (ii < 0 || ii >= H_) continue;
    for (int dj = -1; dj <= 1; dj++) {
      int jj = j + dj; if (jj < 0 || jj >= W_) continue;
      size_t nb = (size_t)((b * H_ + ii) * W_ + jj) * C_;
      double a0 = xold[nb + 3]; if (a0 > mo) mo = a0;
      double a1 = xn[nb + 3];   if (a1 > mn2) mn2 = a1;
    }
  }
  bool life = (mo > 0.1) && (mn2 > 0.1);
  double v = life ? xn[((size_t)cell << 4) + c] : 0.0;
  xout[((size_t)cell << 4) + c] = v;
  out_x[(size_t)n * NCELL * C_ + ((size_t)cell << 4) + c] = (float)v;
}

// ---------------------------------------------------------------------------
// final emission for scan step 64
// ---------------------------------------------------------------------------
__global__ void k_emit(const double* __restrict__ lam, const double* __restrict__ un,
                       float* __restrict__ out_lam, double* __restrict__ p_buf) {
  int cell = blockIdx.x * 256 + threadIdx.x;
  double l = lam[cell];
  size_t o = (size_t)(T_ - 1) * NCELL + cell;
  out_lam[o] = (float)l;
  p_buf[o] = un[cell] * l + 1e-6;
}

// ---------------------------------------------------------------------------
// final: p_norm[t] = p[t] / sum_t p[t]
// ---------------------------------------------------------------------------
__global__ void k_pnorm(const double* __restrict__ p_buf, float* __restrict__ out_p) {
  int cell = blockIdx.x * 256 + threadIdx.x;
  double s = 0.0;
  for (int t = 0; t < T_; t++) s += p_buf[(size_t)t * NCELL + cell];
  for (int t = 0; t < T_; t++)
    out_p[(size_t)t * NCELL + cell] = (float)(p_buf[(size_t)t * NCELL + cell] / s);
}

// ---------------------------------------------------------------------------
extern "C" void kernel_launch(void* const* d_in, const int* in_sizes, int n_in,
                              void* d_out, int out_size, void* d_ws, size_t ws_size,
                              hipStream_t stream) {
  const float* xin = (const float*)d_in[0];
  const float* w1  = (const float*)d_in[1];
  const float* b1  = (const float*)d_in[2];
  const float* w2  = (const float*)d_in[3];
  const float* b2  = (const float*)d_in[4];
  const float* f0w = (const float*)d_in[5];
  const float* f0b = (const float*)d_in[6];
  const float* f1w = (const float*)d_in[7];

  float* out     = (float*)d_out;
  float* out_x   = out;                                   // (64, NCELL, 16)
  float* out_p   = out_x + (size_t)T_ * NCELL * C_;       // (64, NCELL)
  float* out_lam = out_p + (size_t)T_ * NCELL;            // (64, NCELL)
  float* out_upd = out_lam + (size_t)T_ * NCELL;          // (64, NCELL)

  // workspace layout
  double* ws    = (double*)d_ws;
  double* xA    = ws;                                  // NCELL*16
  double* xB    = xA + (size_t)NCELL * C_;             // NCELL*16
  double* xn    = xB + (size_t)NCELL * C_;             // NCELL*16
  double* hbuf  = xn + (size_t)NCELL * C_;             // NCELL*16
  double* lamA  = hbuf + (size_t)NCELL * HP_;          // NCELL
  double* lamB  = lamA + NCELL;                        // NCELL
  double* un    = lamB + NCELL;                        // NCELL
  double* p_buf = un + NCELL;                          // 64*NCELL
  double* weffd = p_buf + (size_t)T_ * NCELL;          // 6400 f64
  float*  fc0tf = (float*)(weffd + 6400);              // 6144 f32

  k_init<<<2592, 256, 0, stream>>>(xin, xA, un);
  k_prep<<<26, 256, 0, stream>>>(w1, f0w, weffd, fc0tf);

  double* cur = lamA;   // lagged lam entering iteration n
  double* nxt = lamB;

  for (int n = 0; n <= T_ - 1; n++) {
    k_conv1<<<1152, 288, 0, stream>>>(xA, weffd, w1, b1, hbuf);
    uint32_t kx0 = 0u, kx1 = (uint32_t)n;
    threefry2x32(0u, 42u, kx0, kx1);
    k_upd<<<648, 512, 0, stream>>>(xA, hbuf, cur, fc0tf, f1w, w2, f0b, b2,
                                   (n == 0 ? cur : nxt), xn, out_upd, un,
                                   out_lam, p_buf, kx0, kx1, n);
    k_life<<<2592, 256, 0, stream>>>(xA, xn, xB, out_x, n);
    { double* t = xA; xA = xB; xB = t; }
    if (n >= 1) { double* t = cur; cur = nxt; nxt = t; }
  }

  // scan step 64: emit lam_steps[63], p_steps[63] from cur = L(perc(x62))
  k_emit<<<162, 256, 0, stream>>>(cur, un, out_lam, p_buf);
  k_pnorm<<<162, 256, 0, stream>>>(p_buf, out_p);
}